// Round 3
// baseline (100.902 us; speedup 1.0000x reference)
//
#include <hip/hip_runtime.h>
#include <hip/hip_bf16.h>
#include <math.h>

// Problem constants (from reference)
#define BATCH   2
#define SEQ     512     // N
#define DIN     512
#define DM      256     // d_model
#define DM4     (DM/4)  // 64 d-quads

#define LOG2E2  2.88539008177792681f   // 2*log2(e)

#if __has_builtin(__builtin_amdgcn_exp2f)
#define EXP2(x) __builtin_amdgcn_exp2f(x)
#else
#define EXP2(x) exp2f(x)
#endif
#if __has_builtin(__builtin_amdgcn_rcpf)
#define RCP(x) __builtin_amdgcn_rcpf(x)
#else
#define RCP(x) (1.0f / (x))
#endif

// tanh(t) with targ = 2*log2(e)*t: tanh = 1 - 2/(1 + exp2(targ)); overflow-safe.
__device__ __forceinline__ float tanh_from_scaled(float targ) {
    return fmaf(-2.0f, RCP(1.0f + EXP2(targ)), 1.0f);
}

// ---------------- Kernel 1: fused EB + h GEMM, global-direct operands --------
// 256 blocks x 512 threads, 1 block/CU.
// r3: NO LDS staging — the r2 loop was LDS-throughput-bound (64 ds_read_b128
// per lane ~= 2.6us/CU > 1.7us FMA floor). Wx read per-wave as ONE contiguous
// 128B segment (c4 lanes dedup), x 8-way dedup'd; each line is consumed once,
// so caching in LDS bought nothing. LDS only for the k-slice combine.
// EB side-work spread over ALL 256 blocks (half a (b,d4) unit each).
__global__ __launch_bounds__(512) void produce_k(
    const float* __restrict__ pos,  // [B, N, 4]
    const float* __restrict__ Wp,   // [4, DM]
    const float* __restrict__ x,    // [B*N, DIN]
    const float* __restrict__ Wx,   // [DIN, DM]
    const float* __restrict__ bx,   // [DM]
    float4* __restrict__ EB4,       // [B][DM4][SEQ] float4
    float* __restrict__ h)          // [B*N, DM]
{
    const int tid = threadIdx.x;
    const int idx = blockIdx.x;     // 0..255

    // ---- EB side-work: block idx does j-half (idx&1) of unit (idx>>1) ----
    if (tid < 256) {
        const int pair = idx >> 1;       // 0..127 = (b, d4)
        const int b  = pair >> 6;
        const int d4 = pair & 63;
        const int d0 = 4 * d4;
        const int j  = (idx & 1) * 256 + tid;
        const float4 p = ((const float4*)pos)[b * SEQ + j];   // coalesced 16B
        float4 e;
        {
            const float P = fmaf(p.x, Wp[d0], fmaf(p.y, Wp[DM + d0],
                            fmaf(p.z, Wp[2*DM + d0], p.w * Wp[3*DM + d0])));
            e.x = EXP2(-LOG2E2 * P);
        }
        {
            const float P = fmaf(p.x, Wp[d0+1], fmaf(p.y, Wp[DM + d0+1],
                            fmaf(p.z, Wp[2*DM + d0+1], p.w * Wp[3*DM + d0+1])));
            e.y = EXP2(-LOG2E2 * P);
        }
        {
            const float P = fmaf(p.x, Wp[d0+2], fmaf(p.y, Wp[DM + d0+2],
                            fmaf(p.z, Wp[2*DM + d0+2], p.w * Wp[3*DM + d0+2])));
            e.z = EXP2(-LOG2E2 * P);
        }
        {
            const float P = fmaf(p.x, Wp[d0+3], fmaf(p.y, Wp[DM + d0+3],
                            fmaf(p.z, Wp[2*DM + d0+3], p.w * Wp[3*DM + d0+3])));
            e.w = EXP2(-LOG2E2 * P);
        }
        EB4[((size_t)(b * DM4 + d4)) * SEQ + j] = e;           // coalesced b128
    }

    __shared__ float s_part[8][32][36];   // 36 KB: k-slice partials

    const int rt = idx >> 3;           // 0..31 row tile -> rows 32*rt..
    const int ct = idx & 7;            // 0..7 col tile  -> cols 32*ct..

    // ---- 4x4 register tile: wave ks owns k-slice [64ks, 64ks+64) ----
    const int ks = __builtin_amdgcn_readfirstlane(tid >> 6);  // wave 0..7
    const int l  = tid & 63;
    const int r4 = l >> 3;             // 0..7 -> rows 4*r4..4*r4+3
    const int c4 = l & 7;              // 0..7 -> cols 4*c4..4*c4+3
    const int k0 = ks * 64;

    const float* __restrict__ xr = x  + (size_t)(rt * 32 + 4 * r4) * DIN + k0;
    const float* __restrict__ wr = Wx + (size_t)k0 * DM + ct * 32 + 4 * c4;

    float4 a0 = make_float4(0.f,0.f,0.f,0.f), a1 = a0, a2 = a0, a3 = a0;

    #pragma unroll 2
    for (int kk = 0; kk < 64; kk += 4) {
        // 4 rows x 4 k: global b128, 8-way lane-dedup (L2-resident stream)
        const float4 x0 = *(const float4*)(xr + kk);
        const float4 x1 = *(const float4*)(xr + kk + DIN);
        const float4 x2 = *(const float4*)(xr + kk + 2 * DIN);
        const float4 x3 = *(const float4*)(xr + kk + 3 * DIN);
#define GSTEP(C, J) { \
        const float4 wq = *(const float4*)(wr + (size_t)(kk + J) * DM); \
        a0.x = fmaf(x0.C, wq.x, a0.x); a0.y = fmaf(x0.C, wq.y, a0.y); \
        a0.z = fmaf(x0.C, wq.z, a0.z); a0.w = fmaf(x0.C, wq.w, a0.w); \
        a1.x = fmaf(x1.C, wq.x, a1.x); a1.y = fmaf(x1.C, wq.y, a1.y); \
        a1.z = fmaf(x1.C, wq.z, a1.z); a1.w = fmaf(x1.C, wq.w, a1.w); \
        a2.x = fmaf(x2.C, wq.x, a2.x); a2.y = fmaf(x2.C, wq.y, a2.y); \
        a2.z = fmaf(x2.C, wq.z, a2.z); a2.w = fmaf(x2.C, wq.w, a2.w); \
        a3.x = fmaf(x3.C, wq.x, a3.x); a3.y = fmaf(x3.C, wq.y, a3.y); \
        a3.z = fmaf(x3.C, wq.z, a3.z); a3.w = fmaf(x3.C, wq.w, a3.w); \
    }
        GSTEP(x, 0) GSTEP(y, 1) GSTEP(z, 2) GSTEP(w, 3)
#undef GSTEP
    }

    // ---- write k-slice partials ----
    *(float4*)&s_part[ks][4 * r4 + 0][4 * c4] = a0;
    *(float4*)&s_part[ks][4 * r4 + 1][4 * c4] = a1;
    *(float4*)&s_part[ks][4 * r4 + 2][4 * c4] = a2;
    *(float4*)&s_part[ks][4 * r4 + 3][4 * c4] = a3;
    __syncthreads();

    // ---- combine 8 partials + bias + tanh + store (256 threads, 4 out each) -
    if (tid < 256) {
        const int row = tid >> 3;      // 0..31
        const int cq  = tid & 7;       // 0..7 -> cols 4*cq..
        float4 s = *(const float4*)&s_part[0][row][4 * cq];
        #pragma unroll
        for (int p = 1; p < 8; p++) {
            const float4 q = *(const float4*)&s_part[p][row][4 * cq];
            s.x += q.x; s.y += q.y; s.z += q.z; s.w += q.w;
        }
        const float4 bq = *(const float4*)(bx + ct * 32 + 4 * cq);
        float4 o;
        o.x = tanh_from_scaled(LOG2E2 * (s.x + bq.x));
        o.y = tanh_from_scaled(LOG2E2 * (s.y + bq.y));
        o.z = tanh_from_scaled(LOG2E2 * (s.z + bq.z));
        o.w = tanh_from_scaled(LOG2E2 * (s.w + bq.w));
        *(float4*)(h + (size_t)(rt * 32 + row) * DM + ct * 32 + 4 * cq) = o;
    }
}

// ---------------- Kernel 2: EA (inline) + scores + softmax + AV --------------
// 256 blocks (4 i-rows each) x 512 threads.
// r3: 16-way rcp merge via pairwise product tree — 62 VALU + 1 rcp per
// 16d per row (vs 56 + 4): issue cycles 132 vs 144 on the dominant phase.
// Safe: prod of 16 y's <= ~1e21 << fp32 max for this data (t std ~0.25).
__global__ __launch_bounds__(512) void attend_k(
    const float* __restrict__ pos,   // [B, N, 4]
    const float* __restrict__ Wp,    // [4, DM]
    const float* __restrict__ bp,    // [DM]
    const int*   __restrict__ mask,  // [B, N, N]
    const float* __restrict__ wv,    // [DM]
    const float4* __restrict__ EB4,  // [B][DM4][SEQ] float4
    const float* __restrict__ h,     // [B, N, DM]
    float* __restrict__ out,         // [B, N, DM]
    float* __restrict__ attn_out)    // [B, N, N]
{
    const int b   = blockIdx.x >> 7;         // 128 blocks per batch
    const int i0  = (blockIdx.x & 127) * 4;  // rows i0..i0+3
    const int tid = threadIdx.x;             // = j in score phase
    const int l   = tid & 63;

    __shared__ float4 s_ea[DM];       // 4 KB: {ea_row0..ea_row3} per d
    __shared__ float  s_p[4][SEQ];    // 8 KB
    __shared__ float  s_red[4][8];
    __shared__ float  s_o[7][4][DM];  // 28 KB

    // ---- EA prologue: thread = (d = tid&255, rp = tid>>8 -> rows {2rp, 2rp+1}) ----
    {
        const int d  = tid & 255;
        const int rp = __builtin_amdgcn_readfirstlane(tid >> 8);   // 0/1
        const int r0 = rp * 2;
        const float4 p0 = ((const float4*)pos)[b * SEQ + i0 + r0];     // uniform s_load
        const float4 p1 = ((const float4*)pos)[b * SEQ + i0 + r0 + 1];
        const float wp0 = Wp[d], wp1 = Wp[DM + d], wp2 = Wp[2*DM + d], wp3 = Wp[3*DM + d];
        const float bpd = bp[d];
        const float P0 = fmaf(p0.x, wp0, fmaf(p0.y, wp1, fmaf(p0.z, wp2, p0.w * wp3)));
        const float P1 = fmaf(p1.x, wp0, fmaf(p1.y, wp1, fmaf(p1.z, wp2, p1.w * wp3)));
        float* se = (float*)&s_ea[d];
        se[r0]     = EXP2(LOG2E2 * (P0 + bpd));
        se[r0 + 1] = EXP2(LOG2E2 * (P1 + bpd));
    }
    __syncthreads();

    // ---- hoisted mask loads (issue now, consume ~8k cycles later) ----
    const size_t mrow = (size_t)b * SEQ * SEQ + (size_t)i0 * SEQ + tid;
    const int m0 = mask[mrow];
    const int m1 = mask[mrow + SEQ];
    const int m2 = mask[mrow + 2*SEQ];
    const int m3 = mask[mrow + 3*SEQ];

    // ---- score: 16 iters x 16 d; 4 coalesced b128 EB loads; 1 rcp/16d/row ---
    const float4* __restrict__ EBj = EB4 + (size_t)b * DM4 * SEQ + tid;   // j = tid

    float a0 = 0.f, a1 = 0.f, a2 = 0.f, a3 = 0.f;
    #pragma unroll 2
    for (int t = 0; t < 16; t++) {
        const float4 eb0 = EBj[(size_t)(4*t + 0) * SEQ];   // dims 16t+0..3
        const float4 eb1 = EBj[(size_t)(4*t + 1) * SEQ];   // dims 16t+4..7
        const float4 eb2 = EBj[(size_t)(4*t + 2) * SEQ];   // dims 16t+8..11
        const float4 eb3 = EBj[(size_t)(4*t + 3) * SEQ];   // dims 16t+12..15
        const float4* __restrict__ ea = &s_ea[16*t];
        const float4 ea0 = ea[0],  ea1 = ea[1],  ea2 = ea[2],  ea3 = ea[3];
        const float4 ea4 = ea[4],  ea5 = ea[5],  ea6 = ea[6],  ea7 = ea[7];
        const float4 ea8 = ea[8],  ea9 = ea[9],  eaA = ea[10], eaB = ea[11];
        const float4 eaC = ea[12], eaD = ea[13], eaE = ea[14], eaF = ea[15];
        const float4 w0 = *(const float4*)(wv + 16*t);        // uniform s_loads
        const float4 w1 = *(const float4*)(wv + 16*t + 4);
        const float4 w2 = *(const float4*)(wv + 16*t + 8);
        const float4 w3 = *(const float4*)(wv + 16*t + 12);

        // per row: quad trees -> one rcp per 16 d
#define QUAD(C, EA0, EA1, EA2, EA3, EBQ, WQ, NQ, QQ) \
        { \
            const float y0 = fmaf(EA0.C, EBQ.x, 1.f); \
            const float y1 = fmaf(EA1.C, EBQ.y, 1.f); \
            const float y2 = fmaf(EA2.C, EBQ.z, 1.f); \
            const float y3 = fmaf(EA3.C, EBQ.w, 1.f); \
            const float q01 = y0 * y1, q23 = y2 * y3; \
            const float n01 = fmaf(WQ.x, y1, WQ.y * y0); \
            const float n23 = fmaf(WQ.z, y3, WQ.w * y2); \
            NQ = fmaf(n01, q23, n23 * q01); \
            QQ = q01 * q23; \
        }
#define SCORE_ROW(acc, C) { \
        float nA, qA, nB, qB, nC, qC, nD, qD; \
        QUAD(C, ea0, ea1, ea2, ea3, eb0, w0, nA, qA) \
        QUAD(C, ea4, ea5, ea6, ea7, eb1, w1, nB, qB) \
        QUAD(C, ea8, ea9, eaA, eaB, eb2, w2, nC, qC) \
        QUAD(C, eaC, eaD, eaE, eaF, eb3, w3, nD, qD) \
        const float nAB = fmaf(nA, qB, nB * qA); \
        const float qAB = qA * qB; \
        const float nCD = fmaf(nC, qD, nD * qC); \
        const float qCD = qC * qD; \
        const float ntot = fmaf(nAB, qCD, nCD * qAB); \
        acc = fmaf(ntot, RCP(qAB * qCD), acc); \
    }
        SCORE_ROW(a0, x)
        SCORE_ROW(a1, y)
        SCORE_ROW(a2, z)
        SCORE_ROW(a3, w)
#undef SCORE_ROW
#undef QUAD
    }

    // ---- masked softmax, 4 rows (score = const - 2a; shift-invariant) ----
    float p0 = m0 ? EXP2(-LOG2E2 * a0) : 0.f;
    float p1 = m1 ? EXP2(-LOG2E2 * a1) : 0.f;
    float p2 = m2 ? EXP2(-LOG2E2 * a2) : 0.f;
    float p3 = m3 ? EXP2(-LOG2E2 * a3) : 0.f;

    float s0 = p0, s1 = p1, s2 = p2, s3 = p3;
    #pragma unroll
    for (int off = 32; off; off >>= 1) {
        s0 += __shfl_xor(s0, off, 64);
        s1 += __shfl_xor(s1, off, 64);
        s2 += __shfl_xor(s2, off, 64);
        s3 += __shfl_xor(s3, off, 64);
    }
    const int w = tid >> 6;   // 0..7
    if (l == 0) { s_red[0][w] = s0; s_red[1][w] = s1; s_red[2][w] = s2; s_red[3][w] = s3; }
    __syncthreads();

    {
        const float4 r0a = ((const float4*)s_red[0])[0], r0b = ((const float4*)s_red[0])[1];
        const float4 r1a = ((const float4*)s_red[1])[0], r1b = ((const float4*)s_red[1])[1];
        const float4 r2a = ((const float4*)s_red[2])[0], r2b = ((const float4*)s_red[2])[1];
        const float4 r3a = ((const float4*)s_red[3])[0], r3b = ((const float4*)s_red[3])[1];
        p0 *= __fdividef(1.0f, (r0a.x+r0a.y+r0a.z+r0a.w) + (r0b.x+r0b.y+r0b.z+r0b.w));
        p1 *= __fdividef(1.0f, (r1a.x+r1a.y+r1a.z+r1a.w) + (r1b.x+r1b.y+r1b.z+r1b.w));
        p2 *= __fdividef(1.0f, (r2a.x+r2a.y+r2a.z+r2a.w) + (r2b.x+r2b.y+r2b.z+r2b.w));
        p3 *= __fdividef(1.0f, (r3a.x+r3a.y+r3a.z+r3a.w) + (r3b.x+r3b.y+r3b.z+r3b.w));
    }

    attn_out[mrow]         = p0;
    attn_out[mrow + SEQ]   = p1;
    attn_out[mrow + 2*SEQ] = p2;
    attn_out[mrow + 3*SEQ] = p3;
    s_p[0][tid] = p0; s_p[1][tid] = p1; s_p[2][tid] = p2; s_p[3][tid] = p3;
    __syncthreads();

    // ---- av: out[i_r, d] = sum_j p_r[j] * h[b,j,d], 4 rows share h loads ----
    const int dq = tid & 63;                                    // 4-d quad
    const int js = __builtin_amdgcn_readfirstlane(tid >> 6);    // 0..7 -> 64-j slice
    const float* __restrict__ hp = h + (size_t)(b * SEQ + js * 64) * DM + 4 * dq;
    const float* __restrict__ q0p = &s_p[0][js * 64];
    const float* __restrict__ q1p = &s_p[1][js * 64];
    const float* __restrict__ q2p = &s_p[2][js * 64];
    const float* __restrict__ q3p = &s_p[3][js * 64];

    float4 a0v = make_float4(0,0,0,0), a1v = a0v, a2v = a0v, a3v = a0v;
    #pragma unroll 4
    for (int jj = 0; jj < 16; jj++) {
        const float4 P0 = *(const float4*)(q0p + 4 * jj);   // b128 broadcast
        const float4 P1 = *(const float4*)(q1p + 4 * jj);
        const float4 P2 = *(const float4*)(q2p + 4 * jj);
        const float4 P3 = *(const float4*)(q3p + 4 * jj);
        const float4 h0 = *(const float4*)(hp + (size_t)(4*jj + 0) * DM);
        const float4 h1 = *(const float4*)(hp + (size_t)(4*jj + 1) * DM);
        const float4 h2 = *(const float4*)(hp + (size_t)(4*jj + 2) * DM);
        const float4 h3 = *(const float4*)(hp + (size_t)(4*jj + 3) * DM);

        a0v.x = fmaf(P0.x,h0.x,fmaf(P0.y,h1.x,fmaf(P0.z,h2.x,fmaf(P0.w,h3.x,a0v.x))));
        a0v.y = fmaf(P0.x,h0.y,fmaf(P0.y,h1.y,fmaf(P0.z,h2.y,fmaf(P0.w,h3.y,a0v.y))));
        a0v.z = fmaf(P0.x,h0.z,fmaf(P0.y,h1.z,fmaf(P0.z,h2.z,fmaf(P0.w,h3.z,a0v.z))));
        a0v.w = fmaf(P0.x,h0.w,fmaf(P0.y,h1.w,fmaf(P0.z,h2.w,fmaf(P0.w,h3.w,a0v.w))));
        a1v.x = fmaf(P1.x,h0.x,fmaf(P1.y,h1.x,fmaf(P1.z,h2.x,fmaf(P1.w,h3.x,a1v.x))));
        a1v.y = fmaf(P1.x,h0.y,fmaf(P1.y,h1.y,fmaf(P1.z,h2.y,fmaf(P1.w,h3.y,a1v.y))));
        a1v.z = fmaf(P1.x,h0.z,fmaf(P1.y,h1.z,fmaf(P1.z,h2.z,fmaf(P1.w,h3.z,a1v.z))));
        a1v.w = fmaf(P1.x,h0.w,fmaf(P1.y,h1.w,fmaf(P1.z,h2.w,fmaf(P1.w,h3.w,a1v.w))));
        a2v.x = fmaf(P2.x,h0.x,fmaf(P2.y,h1.x,fmaf(P2.z,h2.x,fmaf(P2.w,h3.x,a2v.x))));
        a2v.y = fmaf(P2.x,h0.y,fmaf(P2.y,h1.y,fmaf(P2.z,h2.y,fmaf(P2.w,h3.y,a2v.y))));
        a2v.z = fmaf(P2.x,h0.z,fmaf(P2.y,h1.z,fmaf(P2.z,h2.z,fmaf(P2.w,h3.z,a2v.z))));
        a2v.w = fmaf(P2.x,h0.w,fmaf(P2.y,h1.w,fmaf(P2.z,h2.w,fmaf(P2.w,h3.w,a2v.w))));
        a3v.x = fmaf(P3.x,h0.x,fmaf(P3.y,h1.x,fmaf(P3.z,h2.x,fmaf(P3.w,h3.x,a3v.x))));
        a3v.y = fmaf(P3.x,h0.y,fmaf(P3.y,h1.y,fmaf(P3.z,h2.y,fmaf(P3.w,h3.y,a3v.y))));
        a3v.z = fmaf(P3.x,h0.z,fmaf(P3.y,h1.z,fmaf(P3.z,h2.z,fmaf(P3.w,h3.z,a3v.z))));
        a3v.w = fmaf(P3.x,h0.w,fmaf(P3.y,h1.w,fmaf(P3.z,h2.w,fmaf(P3.w,h3.w,a3v.w))));
    }

    if (js > 0) {
        *(float4*)&s_o[js - 1][0][4 * dq] = a0v;
        *(float4*)&s_o[js - 1][1][4 * dq] = a1v;
        *(float4*)&s_o[js - 1][2][4 * dq] = a2v;
        *(float4*)&s_o[js - 1][3][4 * dq] = a3v;
    }
    __syncthreads();
    if (js == 0) {
        #pragma unroll
        for (int s = 0; s < 7; s++) {
            const float4 q0 = *(const float4*)&s_o[s][0][4 * dq];
            const float4 q1 = *(const float4*)&s_o[s][1][4 * dq];
            const float4 q2 = *(const float4*)&s_o[s][2][4 * dq];
            const float4 q3 = *(const float4*)&s_o[s][3][4 * dq];
            a0v.x += q0.x; a0v.y += q0.y; a0v.z += q0.z; a0v.w += q0.w;
            a1v.x += q1.x; a1v.y += q1.y; a1v.z += q1.z; a1v.w += q1.w;
            a2v.x += q2.x; a2v.y += q2.y; a2v.z += q2.z; a2v.w += q2.w;
            a3v.x += q3.x; a3v.y += q3.y; a3v.z += q3.z; a3v.w += q3.w;
        }
        float* __restrict__ op = out + (size_t)(b * SEQ + i0) * DM + 4 * dq;
        *(float4*)(op)        = a0v;
        *(float4*)(op + DM)   = a1v;
        *(float4*)(op + 2*DM) = a2v;
        *(float4*)(op + 3*DM) = a3v;
    }
}

extern "C" void kernel_launch(void* const* d_in, const int* in_sizes, int n_in,
                              void* d_out, int out_size, void* d_ws, size_t ws_size,
                              hipStream_t stream) {
    const float* x    = (const float*)d_in[0];
    const float* pos  = (const float*)d_in[1];
    const int*   mask = (const int*)  d_in[2];
    const float* Wx   = (const float*)d_in[3];
    const float* bx   = (const float*)d_in[4];
    const float* Wp   = (const float*)d_in[5];
    const float* bp   = (const float*)d_in[6];
    const float* wv   = (const float*)d_in[7];

    float* out      = (float*)d_out;                          // [B,N,DM]
    float* attn_out = (float*)d_out + (size_t)BATCH*SEQ*DM;   // [B,N,N]

    char*  ws  = (char*)d_ws;
    float* h   = (float*)(ws);                                // 1 MB
    float* EBf = (float*)(ws + (size_t)BATCH*SEQ*DM*4);       // 1 MB ([B][DM4][SEQ] float4)

    produce_k<<<256, 512, 0, stream>>>(pos, Wp, x, Wx, bx, (float4*)EBf, h);
    attend_k <<<(BATCH*SEQ)/4, 512, 0, stream>>>(pos, Wp, bp, mask, wv,
                                                 (const float4*)EBf, h, out, attn_out);
}

// Round 4
// 97.074 us; speedup vs baseline: 1.0394x; 1.0394x over previous
//
#include <hip/hip_runtime.h>
#include <hip/hip_bf16.h>
#include <math.h>

// Problem constants (from reference)
#define BATCH   2
#define SEQ     512     // N
#define DIN     512
#define DM      256     // d_model
#define DM4     (DM/4)  // 64 d-quads

#define LOG2E2  2.88539008177792681f   // 2*log2(e)

#if __has_builtin(__builtin_amdgcn_exp2f)
#define EXP2(x) __builtin_amdgcn_exp2f(x)
#else
#define EXP2(x) exp2f(x)
#endif
#if __has_builtin(__builtin_amdgcn_rcpf)
#define RCP(x) __builtin_amdgcn_rcpf(x)
#else
#define RCP(x) (1.0f / (x))
#endif

// tanh(t) with targ = 2*log2(e)*t: tanh = 1 - 2/(1 + exp2(targ)); overflow-safe.
__device__ __forceinline__ float tanh_from_scaled(float targ) {
    return fmaf(-2.0f, RCP(1.0f + EXP2(targ)), 1.0f);
}

// ---------- packed fp32 primitives (VOP3P; compiler never auto-emits these) --
// f32x2 lives in an even-aligned VGPR pair; op_sel broadcasts a word of src0.
typedef float f32x2 __attribute__((ext_vector_type(2)));

__device__ __forceinline__ f32x2 pk_fma(f32x2 a, f32x2 b, f32x2 c) {
    f32x2 d;
    asm("v_pk_fma_f32 %0, %1, %2, %3" : "=v"(d) : "v"(a), "v"(b), "v"(c));
    return d;
}
__device__ __forceinline__ f32x2 pk_mul(f32x2 a, f32x2 b) {
    f32x2 d;
    asm("v_pk_mul_f32 %0, %1, %2" : "=v"(d) : "v"(a), "v"(b));
    return d;
}
// d = bcast(a.x) * b + c   (src0 word0 for both halves)
__device__ __forceinline__ f32x2 pk_fma_b0(f32x2 a, f32x2 b, f32x2 c) {
    f32x2 d;
    asm("v_pk_fma_f32 %0, %1, %2, %3 op_sel:[0,0,0] op_sel_hi:[0,1,1]"
        : "=v"(d) : "v"(a), "v"(b), "v"(c));
    return d;
}
// d = bcast(a.y) * b + c   (src0 word1 for both halves)
__device__ __forceinline__ f32x2 pk_fma_b1(f32x2 a, f32x2 b, f32x2 c) {
    f32x2 d;
    asm("v_pk_fma_f32 %0, %1, %2, %3 op_sel:[1,0,0] op_sel_hi:[1,1,1]"
        : "=v"(d) : "v"(a), "v"(b), "v"(c));
    return d;
}
// d = bcast(a.y) * b       (src0 word1 for both halves)
__device__ __forceinline__ f32x2 pk_mul_b1(f32x2 a, f32x2 b) {
    f32x2 d;
    asm("v_pk_mul_f32 %0, %1, %2 op_sel:[1,0] op_sel_hi:[1,1]"
        : "=v"(d) : "v"(a), "v"(b));
    return d;
}

// ---------------- Kernel 1: fused EB quads + h register-tiled GEMM -----------
// 256 blocks x 512 threads, 1 block/CU.  (exact r2 config — 95.9us verified;
// r3's global-direct Wx regressed ~latency-bound, reverted.)
// 4x4 register tile per lane -> 1 ds_read_b128 (8-way bcast) / 16 fma;
// x read straight from global (8-way dedup float4, L1-resident, VMEM pipe);
// Wx staged once (64 KB LDS); k-split-8 across waves; LDS partial combine.
__global__ __launch_bounds__(512) void produce_k(
    const float* __restrict__ pos,  // [B, N, 4]
    const float* __restrict__ Wp,   // [4, DM]
    const float* __restrict__ x,    // [B*N, DIN]
    const float* __restrict__ Wx,   // [DIN, DM]
    const float* __restrict__ bx,   // [DM]
    float4* __restrict__ EB4,       // [B][DM4][SEQ] float4
    float* __restrict__ h)          // [B*N, DM]
{
    const int tid = threadIdx.x;
    const int idx = blockIdx.x;     // 0..255 GEMM tile id

    // ---- EB side-work (first 128 blocks; no LDS, no barrier dependency) ----
    if (idx < 128) {
        const int b  = idx >> 6;
        const int d4 = idx & 63;
        const int d0 = 4 * d4;
        const float4 p = ((const float4*)pos)[b * SEQ + tid];   // coalesced 16B
        float4 e;
        {
            const float P = fmaf(p.x, Wp[d0], fmaf(p.y, Wp[DM + d0],
                            fmaf(p.z, Wp[2*DM + d0], p.w * Wp[3*DM + d0])));
            e.x = EXP2(-LOG2E2 * P);
        }
        {
            const float P = fmaf(p.x, Wp[d0+1], fmaf(p.y, Wp[DM + d0+1],
                            fmaf(p.z, Wp[2*DM + d0+1], p.w * Wp[3*DM + d0+1])));
            e.y = EXP2(-LOG2E2 * P);
        }
        {
            const float P = fmaf(p.x, Wp[d0+2], fmaf(p.y, Wp[DM + d0+2],
                            fmaf(p.z, Wp[2*DM + d0+2], p.w * Wp[3*DM + d0+2])));
            e.z = EXP2(-LOG2E2 * P);
        }
        {
            const float P = fmaf(p.x, Wp[d0+3], fmaf(p.y, Wp[DM + d0+3],
                            fmaf(p.z, Wp[2*DM + d0+3], p.w * Wp[3*DM + d0+3])));
            e.w = EXP2(-LOG2E2 * P);
        }
        EB4[((size_t)(b * DM4 + d4)) * SEQ + tid] = e;           // coalesced b128
    }

    __shared__ float s_w[DIN][32];        // 64 KB: Wx col-slice, pitch 128 B
    __shared__ float s_part[8][32][36];   // 36 KB: k-slice partials, pitch 144 B

    const int rt = idx >> 3;           // 0..31 row tile -> rows 32*rt..
    const int ct = idx & 7;            // 0..7 col tile  -> cols 32*ct..

    // ---- stage Wx[:, 32ct..32ct+31] once: 4096 float4, 8/thread, coalesced --
    #pragma unroll
    for (int s = 0; s < 8; s++) {
        const int q = tid + 512 * s;         // 0..4095
        const int k = q >> 3, c = q & 7;
        *(float4*)&s_w[k][4 * c] =
            *(const float4*)(Wx + (size_t)k * DM + ct * 32 + 4 * c);
    }
    __syncthreads();

    // ---- 4x4 register tile: wave ks owns k-slice [64ks, 64ks+64) ----
    const int ks = __builtin_amdgcn_readfirstlane(tid >> 6);  // wave 0..7
    const int l  = tid & 63;
    const int r4 = l >> 3;             // 0..7 -> rows 4*r4..4*r4+3
    const int c4 = l & 7;              // 0..7 -> cols 4*c4..4*c4+3
    const int k0 = ks * 64;

    const float* __restrict__ xr = x + (size_t)(rt * 32 + 4 * r4) * DIN + k0;

    float4 a0 = make_float4(0.f,0.f,0.f,0.f), a1 = a0, a2 = a0, a3 = a0;

    #pragma unroll 4
    for (int kk = 0; kk < 64; kk += 4) {
        // 4 rows x 4 k: global b128, 8-way lane-dedup (L1-resident tile)
        const float4 x0 = *(const float4*)(xr + kk);
        const float4 x1 = *(const float4*)(xr + kk + DIN);
        const float4 x2 = *(const float4*)(xr + kk + 2 * DIN);
        const float4 x3 = *(const float4*)(xr + kk + 3 * DIN);
#define GSTEP(C, J) { \
        const float4 wq = *(const float4*)&s_w[k0 + kk + J][4 * c4]; \
        a0.x = fmaf(x0.C, wq.x, a0.x); a0.y = fmaf(x0.C, wq.y, a0.y); \
        a0.z = fmaf(x0.C, wq.z, a0.z); a0.w = fmaf(x0.C, wq.w, a0.w); \
        a1.x = fmaf(x1.C, wq.x, a1.x); a1.y = fmaf(x1.C, wq.y, a1.y); \
        a1.z = fmaf(x1.C, wq.z, a1.z); a1.w = fmaf(x1.C, wq.w, a1.w); \
        a2.x = fmaf(x2.C, wq.x, a2.x); a2.y = fmaf(x2.C, wq.y, a2.y); \
        a2.z = fmaf(x2.C, wq.z, a2.z); a2.w = fmaf(x2.C, wq.w, a2.w); \
        a3.x = fmaf(x3.C, wq.x, a3.x); a3.y = fmaf(x3.C, wq.y, a3.y); \
        a3.z = fmaf(x3.C, wq.z, a3.z); a3.w = fmaf(x3.C, wq.w, a3.w); \
    }
        GSTEP(x, 0) GSTEP(y, 1) GSTEP(z, 2) GSTEP(w, 3)
#undef GSTEP
    }

    // ---- write k-slice partials (pitch 36 -> ~2-way aliasing = free) ----
    *(float4*)&s_part[ks][4 * r4 + 0][4 * c4] = a0;
    *(float4*)&s_part[ks][4 * r4 + 1][4 * c4] = a1;
    *(float4*)&s_part[ks][4 * r4 + 2][4 * c4] = a2;
    *(float4*)&s_part[ks][4 * r4 + 3][4 * c4] = a3;
    __syncthreads();

    // ---- combine 8 partials + bias + tanh + store (256 threads, 4 out each) -
    if (tid < 256) {
        const int row = tid >> 3;      // 0..31
        const int cq  = tid & 7;       // 0..7 -> cols 4*cq..
        float4 s = *(const float4*)&s_part[0][row][4 * cq];
        #pragma unroll
        for (int p = 1; p < 8; p++) {
            const float4 q = *(const float4*)&s_part[p][row][4 * cq];
            s.x += q.x; s.y += q.y; s.z += q.z; s.w += q.w;
        }
        const float4 bq = *(const float4*)(bx + ct * 32 + 4 * cq);
        float4 o;
        o.x = tanh_from_scaled(LOG2E2 * (s.x + bq.x));
        o.y = tanh_from_scaled(LOG2E2 * (s.y + bq.y));
        o.z = tanh_from_scaled(LOG2E2 * (s.z + bq.z));
        o.w = tanh_from_scaled(LOG2E2 * (s.w + bq.w));
        *(float4*)(h + (size_t)(rt * 32 + row) * DM + ct * 32 + 4 * cq) = o;
    }
}

// ---------------- Kernel 2: EA (inline) + scores + softmax + AV --------------
// 256 blocks (4 i-rows each) x 512 threads.
// r4: score loop in PACKED fp32 (v_pk_fma_f32) — 4 rows as two f32x2 streams
// (s_ea float4 .xy/.zw are free pairs); eb/w broadcasts via op_sel on free
// adjacent pairs. 28 pk + 4 rcp per 4d (88 cy) vs scalar 14x4 + 4 rcp (144 cy).
// Same fma/rcp tree -> bit-identical results.
__global__ __launch_bounds__(512) void attend_k(
    const float* __restrict__ pos,   // [B, N, 4]
    const float* __restrict__ Wp,    // [4, DM]
    const float* __restrict__ bp,    // [DM]
    const int*   __restrict__ mask,  // [B, N, N]
    const float* __restrict__ wv,    // [DM]
    const float4* __restrict__ EB4,  // [B][DM4][SEQ] float4
    const float* __restrict__ h,     // [B, N, DM]
    float* __restrict__ out,         // [B, N, DM]
    float* __restrict__ attn_out)    // [B, N, N]
{
    const int b   = blockIdx.x >> 7;         // 128 blocks per batch
    const int i0  = (blockIdx.x & 127) * 4;  // rows i0..i0+3
    const int tid = threadIdx.x;             // = j in score phase
    const int l   = tid & 63;

    __shared__ float4 s_ea[DM];       // 4 KB: {ea_row0..ea_row3} per d
    __shared__ float  s_p[4][SEQ];    // 8 KB
    __shared__ float  s_red[4][8];
    __shared__ float  s_o[7][4][DM];  // 28 KB

    // ---- EA prologue: thread = (d = tid&255, rp = tid>>8 -> rows {2rp, 2rp+1}) ----
    {
        const int d  = tid & 255;
        const int rp = __builtin_amdgcn_readfirstlane(tid >> 8);   // 0/1
        const int r0 = rp * 2;
        const float4 p0 = ((const float4*)pos)[b * SEQ + i0 + r0];     // uniform s_load
        const float4 p1 = ((const float4*)pos)[b * SEQ + i0 + r0 + 1];
        const float wp0 = Wp[d], wp1 = Wp[DM + d], wp2 = Wp[2*DM + d], wp3 = Wp[3*DM + d];
        const float bpd = bp[d];
        const float P0 = fmaf(p0.x, wp0, fmaf(p0.y, wp1, fmaf(p0.z, wp2, p0.w * wp3)));
        const float P1 = fmaf(p1.x, wp0, fmaf(p1.y, wp1, fmaf(p1.z, wp2, p1.w * wp3)));
        float* se = (float*)&s_ea[d];
        se[r0]     = EXP2(LOG2E2 * (P0 + bpd));
        se[r0 + 1] = EXP2(LOG2E2 * (P1 + bpd));
    }
    __syncthreads();

    // ---- hoisted mask loads (issue now, consume ~8k cycles later) ----
    const size_t mrow = (size_t)b * SEQ * SEQ + (size_t)i0 * SEQ + tid;
    const int m0 = mask[mrow];
    const int m1 = mask[mrow + SEQ];
    const int m2 = mask[mrow + 2*SEQ];
    const int m3 = mask[mrow + 3*SEQ];

    // ---- score: 64 d-quad iters; packed quad-merged rcp ----
    const float4* __restrict__ EBj = EB4 + (size_t)b * DM4 * SEQ + tid;   // j = tid

    const f32x2 ones = {1.f, 1.f};
    f32x2 accLo = {0.f, 0.f};   // rows 0,1
    f32x2 accHi = {0.f, 0.f};   // rows 2,3
    #pragma unroll 4
    for (int t = 0; t < DM4; t++) {
        const float4 eb = EBj[(size_t)t * SEQ];    // b128 coalesced (L2-hot)
        const float4 e0 = s_ea[4*t + 0];           // b128 broadcast (4 rows, d=4t)
        const float4 e1 = s_ea[4*t + 1];
        const float4 e2 = s_ea[4*t + 2];
        const float4 e3 = s_ea[4*t + 3];
        const float4 w4 = *(const float4*)(wv + 4*t);   // uniform s_load_dwordx4

        // free register pairs (adjacent components of loaded vectors)
        const f32x2 ebxy = {eb.x, eb.y}, ebzw = {eb.z, eb.w};
        const f32x2 wxy  = {w4.x, w4.y}, wzw  = {w4.z, w4.w};
        const f32x2 e0lo = {e0.x, e0.y}, e0hi = {e0.z, e0.w};
        const f32x2 e1lo = {e1.x, e1.y}, e1hi = {e1.z, e1.w};
        const f32x2 e2lo = {e2.x, e2.y}, e2hi = {e2.z, e2.w};
        const f32x2 e3lo = {e3.x, e3.y}, e3hi = {e3.z, e3.w};

        // per row-pair: y_d = 1 + EA_r(d)*EB_j(d); quad-merged single rcp:
        // acc += [ (w0 y1 + w1 y0) q23 + (w2 y3 + w3 y2) q01 ] / (q01 q23)
#define SCORE_PAIR(ACC, E0, E1, E2, E3) { \
        const f32x2 y0 = pk_fma_b0(ebxy, E0, ones); \
        const f32x2 y1 = pk_fma_b1(ebxy, E1, ones); \
        const f32x2 y2 = pk_fma_b0(ebzw, E2, ones); \
        const f32x2 y3 = pk_fma_b1(ebzw, E3, ones); \
        const f32x2 q01 = pk_mul(y0, y1); \
        const f32x2 q23 = pk_mul(y2, y3); \
        const f32x2 n01 = pk_fma_b0(wxy, y1, pk_mul_b1(wxy, y0)); \
        const f32x2 n23 = pk_fma_b0(wzw, y3, pk_mul_b1(wzw, y2)); \
        const f32x2 ntot = pk_fma(n01, q23, pk_mul(n23, q01)); \
        const f32x2 den  = pk_mul(q01, q23); \
        f32x2 r; r.x = RCP(den.x); r.y = RCP(den.y); \
        ACC = pk_fma(ntot, r, ACC); \
    }
        SCORE_PAIR(accLo, e0lo, e1lo, e2lo, e3lo)
        SCORE_PAIR(accHi, e0hi, e1hi, e2hi, e3hi)
#undef SCORE_PAIR
    }
    const float a0 = accLo.x, a1 = accLo.y, a2 = accHi.x, a3 = accHi.y;

    // ---- masked softmax, 4 rows (score = const - 2a; shift-invariant) ----
    float p0 = m0 ? EXP2(-LOG2E2 * a0) : 0.f;
    float p1 = m1 ? EXP2(-LOG2E2 * a1) : 0.f;
    float p2 = m2 ? EXP2(-LOG2E2 * a2) : 0.f;
    float p3 = m3 ? EXP2(-LOG2E2 * a3) : 0.f;

    float s0 = p0, s1 = p1, s2 = p2, s3 = p3;
    #pragma unroll
    for (int off = 32; off; off >>= 1) {
        s0 += __shfl_xor(s0, off, 64);
        s1 += __shfl_xor(s1, off, 64);
        s2 += __shfl_xor(s2, off, 64);
        s3 += __shfl_xor(s3, off, 64);
    }
    const int w = tid >> 6;   // 0..7
    if (l == 0) { s_red[0][w] = s0; s_red[1][w] = s1; s_red[2][w] = s2; s_red[3][w] = s3; }
    __syncthreads();

    {
        const float4 r0a = ((const float4*)s_red[0])[0], r0b = ((const float4*)s_red[0])[1];
        const float4 r1a = ((const float4*)s_red[1])[0], r1b = ((const float4*)s_red[1])[1];
        const float4 r2a = ((const float4*)s_red[2])[0], r2b = ((const float4*)s_red[2])[1];
        const float4 r3a = ((const float4*)s_red[3])[0], r3b = ((const float4*)s_red[3])[1];
        p0 *= __fdividef(1.0f, (r0a.x+r0a.y+r0a.z+r0a.w) + (r0b.x+r0b.y+r0b.z+r0b.w));
        p1 *= __fdividef(1.0f, (r1a.x+r1a.y+r1a.z+r1a.w) + (r1b.x+r1b.y+r1b.z+r1b.w));
        p2 *= __fdividef(1.0f, (r2a.x+r2a.y+r2a.z+r2a.w) + (r2b.x+r2b.y+r2b.z+r2b.w));
        p3 *= __fdividef(1.0f, (r3a.x+r3a.y+r3a.z+r3a.w) + (r3b.x+r3b.y+r3b.z+r3b.w));
    }

    attn_out[mrow]         = p0;
    attn_out[mrow + SEQ]   = p1;
    attn_out[mrow + 2*SEQ] = p2;
    attn_out[mrow + 3*SEQ] = p3;
    s_p[0][tid] = p0; s_p[1][tid] = p1; s_p[2][tid] = p2; s_p[3][tid] = p3;
    __syncthreads();

    // ---- av: out[i_r, d] = sum_j p_r[j] * h[b,j,d], 4 rows share h loads ----
    const int dq = tid & 63;                                    // 4-d quad
    const int js = __builtin_amdgcn_readfirstlane(tid >> 6);    // 0..7 -> 64-j slice
    const float* __restrict__ hp = h + (size_t)(b * SEQ + js * 64) * DM + 4 * dq;
    const float* __restrict__ q0p = &s_p[0][js * 64];
    const float* __restrict__ q1p = &s_p[1][js * 64];
    const float* __restrict__ q2p = &s_p[2][js * 64];
    const float* __restrict__ q3p = &s_p[3][js * 64];

    float4 a0v = make_float4(0,0,0,0), a1v = a0v, a2v = a0v, a3v = a0v;
    #pragma unroll 4
    for (int jj = 0; jj < 16; jj++) {
        const float4 P0 = *(const float4*)(q0p + 4 * jj);   // b128 broadcast
        const float4 P1 = *(const float4*)(q1p + 4 * jj);
        const float4 P2 = *(const float4*)(q2p + 4 * jj);
        const float4 P3 = *(const float4*)(q3p + 4 * jj);
        const float4 h0 = *(const float4*)(hp + (size_t)(4*jj + 0) * DM);
        const float4 h1 = *(const float4*)(hp + (size_t)(4*jj + 1) * DM);
        const float4 h2 = *(const float4*)(hp + (size_t)(4*jj + 2) * DM);
        const float4 h3 = *(const float4*)(hp + (size_t)(4*jj + 3) * DM);

        a0v.x = fmaf(P0.x,h0.x,fmaf(P0.y,h1.x,fmaf(P0.z,h2.x,fmaf(P0.w,h3.x,a0v.x))));
        a0v.y = fmaf(P0.x,h0.y,fmaf(P0.y,h1.y,fmaf(P0.z,h2.y,fmaf(P0.w,h3.y,a0v.y))));
        a0v.z = fmaf(P0.x,h0.z,fmaf(P0.y,h1.z,fmaf(P0.z,h2.z,fmaf(P0.w,h3.z,a0v.z))));
        a0v.w = fmaf(P0.x,h0.w,fmaf(P0.y,h1.w,fmaf(P0.z,h2.w,fmaf(P0.w,h3.w,a0v.w))));
        a1v.x = fmaf(P1.x,h0.x,fmaf(P1.y,h1.x,fmaf(P1.z,h2.x,fmaf(P1.w,h3.x,a1v.x))));
        a1v.y = fmaf(P1.x,h0.y,fmaf(P1.y,h1.y,fmaf(P1.z,h2.y,fmaf(P1.w,h3.y,a1v.y))));
        a1v.z = fmaf(P1.x,h0.z,fmaf(P1.y,h1.z,fmaf(P1.z,h2.z,fmaf(P1.w,h3.z,a1v.z))));
        a1v.w = fmaf(P1.x,h0.w,fmaf(P1.y,h1.w,fmaf(P1.z,h2.w,fmaf(P1.w,h3.w,a1v.w))));
        a2v.x = fmaf(P2.x,h0.x,fmaf(P2.y,h1.x,fmaf(P2.z,h2.x,fmaf(P2.w,h3.x,a2v.x))));
        a2v.y = fmaf(P2.x,h0.y,fmaf(P2.y,h1.y,fmaf(P2.z,h2.y,fmaf(P2.w,h3.y,a2v.y))));
        a2v.z = fmaf(P2.x,h0.z,fmaf(P2.y,h1.z,fmaf(P2.z,h2.z,fmaf(P2.w,h3.z,a2v.z))));
        a2v.w = fmaf(P2.x,h0.w,fmaf(P2.y,h1.w,fmaf(P2.z,h2.w,fmaf(P2.w,h3.w,a2v.w))));
        a3v.x = fmaf(P3.x,h0.x,fmaf(P3.y,h1.x,fmaf(P3.z,h2.x,fmaf(P3.w,h3.x,a3v.x))));
        a3v.y = fmaf(P3.x,h0.y,fmaf(P3.y,h1.y,fmaf(P3.z,h2.y,fmaf(P3.w,h3.y,a3v.y))));
        a3v.z = fmaf(P3.x,h0.z,fmaf(P3.y,h1.z,fmaf(P3.z,h2.z,fmaf(P3.w,h3.z,a3v.z))));
        a3v.w = fmaf(P3.x,h0.w,fmaf(P3.y,h1.w,fmaf(P3.z,h2.w,fmaf(P3.w,h3.w,a3v.w))));
    }

    if (js > 0) {
        *(float4*)&s_o[js - 1][0][4 * dq] = a0v;
        *(float4*)&s_o[js - 1][1][4 * dq] = a1v;
        *(float4*)&s_o[js - 1][2][4 * dq] = a2v;
        *(float4*)&s_o[js - 1][3][4 * dq] = a3v;
    }
    __syncthreads();
    if (js == 0) {
        #pragma unroll
        for (int s = 0; s < 7; s++) {
            const float4 q0 = *(const float4*)&s_o[s][0][4 * dq];
            const float4 q1 = *(const float4*)&s_o[s][1][4 * dq];
            const float4 q2 = *(const float4*)&s_o[s][2][4 * dq];
            const float4 q3 = *(const float4*)&s_o[s][3][4 * dq];
            a0v.x += q0.x; a0v.y += q0.y; a0v.z += q0.z; a0v.w += q0.w;
            a1v.x += q1.x; a1v.y += q1.y; a1v.z += q1.z; a1v.w += q1.w;
            a2v.x += q2.x; a2v.y += q2.y; a2v.z += q2.z; a2v.w += q2.w;
            a3v.x += q3.x; a3v.y += q3.y; a3v.z += q3.z; a3v.w += q3.w;
        }
        float* __restrict__ op = out + (size_t)(b * SEQ + i0) * DM + 4 * dq;
        *(float4*)(op)        = a0v;
        *(float4*)(op + DM)   = a1v;
        *(float4*)(op + 2*DM) = a2v;
        *(float4*)(op + 3*DM) = a3v;
    }
}

extern "C" void kernel_launch(void* const* d_in, const int* in_sizes, int n_in,
                              void* d_out, int out_size, void* d_ws, size_t ws_size,
                              hipStream_t stream) {
    const float* x    = (const float*)d_in[0];
    const float* pos  = (const float*)d_in[1];
    const int*   mask = (const int*)  d_in[2];
    const float* Wx   = (const float*)d_in[3];
    const float* bx   = (const float*)d_in[4];
    const float* Wp   = (const float*)d_in[5];
    const float* bp   = (const float*)d_in[6];
    const float* wv   = (const float*)d_in[7];

    float* out      = (float*)d_out;                          // [B,N,DM]
    float* attn_out = (float*)d_out + (size_t)BATCH*SEQ*DM;   // [B,N,N]

    char*  ws  = (char*)d_ws;
    float* h   = (float*)(ws);                                // 1 MB
    float* EBf = (float*)(ws + (size_t)BATCH*SEQ*DM*4);       // 1 MB ([B][DM4][SEQ] float4)

    produce_k<<<256, 512, 0, stream>>>(pos, Wp, x, Wx, bx, (float4*)EBf, h);
    attend_k <<<(BATCH*SEQ)/4, 512, 0, stream>>>(pos, Wp, bp, mask, wv,
                                                 (const float4*)EBf, h, out, attn_out);
}

// Round 7
// 95.600 us; speedup vs baseline: 1.0555x; 1.0154x over previous
//
#include <hip/hip_runtime.h>
#include <hip/hip_bf16.h>
#include <math.h>

// Problem constants (from reference)
#define BATCH   2
#define SEQ     512     // N
#define DIN     512
#define DM      256     // d_model
#define DM4     (DM/4)  // 64 d-quads

#define LOG2E2  2.88539008177792681f   // 2*log2(e)

#if __has_builtin(__builtin_amdgcn_exp2f)
#define EXP2(x) __builtin_amdgcn_exp2f(x)
#else
#define EXP2(x) exp2f(x)
#endif
#if __has_builtin(__builtin_amdgcn_rcpf)
#define RCP(x) __builtin_amdgcn_rcpf(x)
#else
#define RCP(x) (1.0f / (x))
#endif

// tanh(t) with targ = 2*log2(e)*t: tanh = 1 - 2/(1 + exp2(targ)); overflow-safe.
__device__ __forceinline__ float tanh_from_scaled(float targ) {
    return fmaf(-2.0f, RCP(1.0f + EXP2(targ)), 1.0f);
}

// ---------------- Kernel 1: fused EB quads + h register-tiled GEMM -----------
// 256 blocks x 512 threads, 1 block/CU.  (r2-verified config, 95.9us total.)
// 4x4 register tile per lane -> 1 ds_read_b128 (8-way bcast) / 16 fma;
// x read straight from global (8-way dedup float4, L1-resident, VMEM pipe);
// Wx staged once (64 KB LDS); k-split-8 across waves; LDS partial combine.
__global__ __launch_bounds__(512) void produce_k(
    const float* __restrict__ pos,  // [B, N, 4]
    const float* __restrict__ Wp,   // [4, DM]
    const float* __restrict__ x,    // [B*N, DIN]
    const float* __restrict__ Wx,   // [DIN, DM]
    const float* __restrict__ bx,   // [DM]
    float4* __restrict__ EB4,       // [B][DM4][SEQ] float4
    float* __restrict__ h)          // [B*N, DM]
{
    const int tid = threadIdx.x;
    const int idx = blockIdx.x;     // 0..255 GEMM tile id

    // ---- EB side-work (first 128 blocks; no LDS, no barrier dependency) ----
    if (idx < 128) {
        const int b  = idx >> 6;
        const int d4 = idx & 63;
        const int d0 = 4 * d4;
        const float4 p = ((const float4*)pos)[b * SEQ + tid];   // coalesced 16B
        float4 e;
        {
            const float P = fmaf(p.x, Wp[d0], fmaf(p.y, Wp[DM + d0],
                            fmaf(p.z, Wp[2*DM + d0], p.w * Wp[3*DM + d0])));
            e.x = EXP2(-LOG2E2 * P);
        }
        {
            const float P = fmaf(p.x, Wp[d0+1], fmaf(p.y, Wp[DM + d0+1],
                            fmaf(p.z, Wp[2*DM + d0+1], p.w * Wp[3*DM + d0+1])));
            e.y = EXP2(-LOG2E2 * P);
        }
        {
            const float P = fmaf(p.x, Wp[d0+2], fmaf(p.y, Wp[DM + d0+2],
                            fmaf(p.z, Wp[2*DM + d0+2], p.w * Wp[3*DM + d0+2])));
            e.z = EXP2(-LOG2E2 * P);
        }
        {
            const float P = fmaf(p.x, Wp[d0+3], fmaf(p.y, Wp[DM + d0+3],
                            fmaf(p.z, Wp[2*DM + d0+3], p.w * Wp[3*DM + d0+3])));
            e.w = EXP2(-LOG2E2 * P);
        }
        EB4[((size_t)(b * DM4 + d4)) * SEQ + tid] = e;           // coalesced b128
    }

    __shared__ float s_w[DIN][32];        // 64 KB: Wx col-slice, pitch 128 B
    __shared__ float s_part[8][32][36];   // 36 KB: k-slice partials, pitch 144 B

    const int rt = idx >> 3;           // 0..31 row tile -> rows 32*rt..
    const int ct = idx & 7;            // 0..7 col tile  -> cols 32*ct..

    // ---- stage Wx[:, 32ct..32ct+31] once: 4096 float4, 8/thread, coalesced --
    #pragma unroll
    for (int s = 0; s < 8; s++) {
        const int q = tid + 512 * s;         // 0..4095
        const int k = q >> 3, c = q & 7;
        *(float4*)&s_w[k][4 * c] =
            *(const float4*)(Wx + (size_t)k * DM + ct * 32 + 4 * c);
    }
    __syncthreads();

    // ---- 4x4 register tile: wave ks owns k-slice [64ks, 64ks+64) ----
    const int ks = __builtin_amdgcn_readfirstlane(tid >> 6);  // wave 0..7
    const int l  = tid & 63;
    const int r4 = l >> 3;             // 0..7 -> rows 4*r4..4*r4+3
    const int c4 = l & 7;              // 0..7 -> cols 4*c4..4*c4+3
    const int k0 = ks * 64;

    const float* __restrict__ xr = x + (size_t)(rt * 32 + 4 * r4) * DIN + k0;

    float4 a0 = make_float4(0.f,0.f,0.f,0.f), a1 = a0, a2 = a0, a3 = a0;

    #pragma unroll 4
    for (int kk = 0; kk < 64; kk += 4) {
        // 4 rows x 4 k: global b128, 8-way lane-dedup (L1-resident tile)
        const float4 x0 = *(const float4*)(xr + kk);
        const float4 x1 = *(const float4*)(xr + kk + DIN);
        const float4 x2 = *(const float4*)(xr + kk + 2 * DIN);
        const float4 x3 = *(const float4*)(xr + kk + 3 * DIN);
#define GSTEP(C, J) { \
        const float4 wq = *(const float4*)&s_w[k0 + kk + J][4 * c4]; \
        a0.x = fmaf(x0.C, wq.x, a0.x); a0.y = fmaf(x0.C, wq.y, a0.y); \
        a0.z = fmaf(x0.C, wq.z, a0.z); a0.w = fmaf(x0.C, wq.w, a0.w); \
        a1.x = fmaf(x1.C, wq.x, a1.x); a1.y = fmaf(x1.C, wq.y, a1.y); \
        a1.z = fmaf(x1.C, wq.z, a1.z); a1.w = fmaf(x1.C, wq.w, a1.w); \
        a2.x = fmaf(x2.C, wq.x, a2.x); a2.y = fmaf(x2.C, wq.y, a2.y); \
        a2.z = fmaf(x2.C, wq.z, a2.z); a2.w = fmaf(x2.C, wq.w, a2.w); \
        a3.x = fmaf(x3.C, wq.x, a3.x); a3.y = fmaf(x3.C, wq.y, a3.y); \
        a3.z = fmaf(x3.C, wq.z, a3.z); a3.w = fmaf(x3.C, wq.w, a3.w); \
    }
        GSTEP(x, 0) GSTEP(y, 1) GSTEP(z, 2) GSTEP(w, 3)
#undef GSTEP
    }

    // ---- write k-slice partials (pitch 36 -> ~2-way aliasing = free) ----
    *(float4*)&s_part[ks][4 * r4 + 0][4 * c4] = a0;
    *(float4*)&s_part[ks][4 * r4 + 1][4 * c4] = a1;
    *(float4*)&s_part[ks][4 * r4 + 2][4 * c4] = a2;
    *(float4*)&s_part[ks][4 * r4 + 3][4 * c4] = a3;
    __syncthreads();

    // ---- combine 8 partials + bias + tanh + store (256 threads, 4 out each) -
    if (tid < 256) {
        const int row = tid >> 3;      // 0..31
        const int cq  = tid & 7;       // 0..7 -> cols 4*cq..
        float4 s = *(const float4*)&s_part[0][row][4 * cq];
        #pragma unroll
        for (int p = 1; p < 8; p++) {
            const float4 q = *(const float4*)&s_part[p][row][4 * cq];
            s.x += q.x; s.y += q.y; s.z += q.z; s.w += q.w;
        }
        const float4 bq = *(const float4*)(bx + ct * 32 + 4 * cq);
        float4 o;
        o.x = tanh_from_scaled(LOG2E2 * (s.x + bq.x));
        o.y = tanh_from_scaled(LOG2E2 * (s.y + bq.y));
        o.z = tanh_from_scaled(LOG2E2 * (s.z + bq.z));
        o.w = tanh_from_scaled(LOG2E2 * (s.w + bq.w));
        *(float4*)(h + (size_t)(rt * 32 + row) * DM + ct * 32 + 4 * cq) = o;
    }
}

// ---------------- Kernel 2: EA (inline) + scores + softmax + AV --------------
// 256 blocks (4 i-rows each) x 512 threads.  (r2-verified scalar score loop:
// quad-merged rcp, 13 VALU + 1 rcp per 4d per row; unroll 4 = 576cy window
// covers EBf L2/L3 latency. pk-fp32 variants r4/r5/r6 were slower or broken.)
__global__ __launch_bounds__(512) void attend_k(
    const float* __restrict__ pos,   // [B, N, 4]
    const float* __restrict__ Wp,    // [4, DM]
    const float* __restrict__ bp,    // [DM]
    const int*   __restrict__ mask,  // [B, N, N]
    const float* __restrict__ wv,    // [DM]
    const float4* __restrict__ EB4,  // [B][DM4][SEQ] float4
    const float* __restrict__ h,     // [B, N, DM]
    float* __restrict__ out,         // [B, N, DM]
    float* __restrict__ attn_out)    // [B, N, N]
{
    const int b   = blockIdx.x >> 7;         // 128 blocks per batch
    const int i0  = (blockIdx.x & 127) * 4;  // rows i0..i0+3
    const int tid = threadIdx.x;             // = j in score phase
    const int l   = tid & 63;

    __shared__ float4 s_ea[DM];       // 4 KB: {ea_row0..ea_row3} per d
    __shared__ float  s_p[4][SEQ];    // 8 KB
    __shared__ float  s_red[4][8];
    __shared__ float  s_o[7][4][DM];  // 28 KB

    // ---- EA prologue: thread = (d = tid&255, rp = tid>>8 -> rows {2rp, 2rp+1}) ----
    {
        const int d  = tid & 255;
        const int rp = __builtin_amdgcn_readfirstlane(tid >> 8);   // 0/1
        const int r0 = rp * 2;
        const float4 p0 = ((const float4*)pos)[b * SEQ + i0 + r0];     // uniform s_load
        const float4 p1 = ((const float4*)pos)[b * SEQ + i0 + r0 + 1];
        const float wp0 = Wp[d], wp1 = Wp[DM + d], wp2 = Wp[2*DM + d], wp3 = Wp[3*DM + d];
        const float bpd = bp[d];
        const float P0 = fmaf(p0.x, wp0, fmaf(p0.y, wp1, fmaf(p0.z, wp2, p0.w * wp3)));
        const float P1 = fmaf(p1.x, wp0, fmaf(p1.y, wp1, fmaf(p1.z, wp2, p1.w * wp3)));
        float* se = (float*)&s_ea[d];
        se[r0]     = EXP2(LOG2E2 * (P0 + bpd));
        se[r0 + 1] = EXP2(LOG2E2 * (P1 + bpd));
    }
    __syncthreads();

    // ---- hoisted mask loads (issue now, consume ~8k cycles later) ----
    const size_t mrow = (size_t)b * SEQ * SEQ + (size_t)i0 * SEQ + tid;
    const int m0 = mask[mrow];
    const int m1 = mask[mrow + SEQ];
    const int m2 = mask[mrow + 2*SEQ];
    const int m3 = mask[mrow + 3*SEQ];

    // ---- score: 64 d-quad iters; 1 coalesced b128 EB load; quad-merged rcp --
    const float4* __restrict__ EBj = EB4 + (size_t)b * DM4 * SEQ + tid;   // j = tid

    float a0 = 0.f, a1 = 0.f, a2 = 0.f, a3 = 0.f;
    #pragma unroll 4
    for (int t = 0; t < DM4; t++) {
        const float4 eb = EBj[(size_t)t * SEQ];    // b128 coalesced (L2-hot)
        const float4 e0 = s_ea[4*t + 0];           // b128 broadcast (4 rows, d=4t)
        const float4 e1 = s_ea[4*t + 1];
        const float4 e2 = s_ea[4*t + 2];
        const float4 e3 = s_ea[4*t + 3];
        const float4 w4 = *(const float4*)(wv + 4*t);   // uniform s_load_dwordx4

        // a_r += w0/y0 + w1/y1 + w2/y2 + w3/y3, quad-merged (1 rcp):
        //      = [n01*q23 + n23*q01] * rcp(q01*q23)
#define SCORE_ROW(acc, C) { \
        const float y0 = fmaf(e0.C, eb.x, 1.f); \
        const float y1 = fmaf(e1.C, eb.y, 1.f); \
        const float y2 = fmaf(e2.C, eb.z, 1.f); \
        const float y3 = fmaf(e3.C, eb.w, 1.f); \
        const float q01 = y0 * y1, q23 = y2 * y3; \
        const float n01 = fmaf(w4.x, y1, w4.y * y0); \
        const float n23 = fmaf(w4.z, y3, w4.w * y2); \
        acc = fmaf(fmaf(n01, q23, n23 * q01), RCP(q01 * q23), acc); \
    }
        SCORE_ROW(a0, x)
        SCORE_ROW(a1, y)
        SCORE_ROW(a2, z)
        SCORE_ROW(a3, w)
#undef SCORE_ROW
    }

    // ---- masked softmax, 4 rows (score = const - 2a; shift-invariant) ----
    float p0 = m0 ? EXP2(-LOG2E2 * a0) : 0.f;
    float p1 = m1 ? EXP2(-LOG2E2 * a1) : 0.f;
    float p2 = m2 ? EXP2(-LOG2E2 * a2) : 0.f;
    float p3 = m3 ? EXP2(-LOG2E2 * a3) : 0.f;

    float s0 = p0, s1 = p1, s2 = p2, s3 = p3;
    #pragma unroll
    for (int off = 32; off; off >>= 1) {
        s0 += __shfl_xor(s0, off, 64);
        s1 += __shfl_xor(s1, off, 64);
        s2 += __shfl_xor(s2, off, 64);
        s3 += __shfl_xor(s3, off, 64);
    }
    const int w = tid >> 6;   // 0..7
    if (l == 0) { s_red[0][w] = s0; s_red[1][w] = s1; s_red[2][w] = s2; s_red[3][w] = s3; }
    __syncthreads();

    {
        const float4 r0a = ((const float4*)s_red[0])[0], r0b = ((const float4*)s_red[0])[1];
        const float4 r1a = ((const float4*)s_red[1])[0], r1b = ((const float4*)s_red[1])[1];
        const float4 r2a = ((const float4*)s_red[2])[0], r2b = ((const float4*)s_red[2])[1];
        const float4 r3a = ((const float4*)s_red[3])[0], r3b = ((const float4*)s_red[3])[1];
        p0 *= __fdividef(1.0f, (r0a.x+r0a.y+r0a.z+r0a.w) + (r0b.x+r0b.y+r0b.z+r0b.w));
        p1 *= __fdividef(1.0f, (r1a.x+r1a.y+r1a.z+r1a.w) + (r1b.x+r1b.y+r1b.z+r1b.w));
        p2 *= __fdividef(1.0f, (r2a.x+r2a.y+r2a.z+r2a.w) + (r2b.x+r2b.y+r2b.z+r2b.w));
        p3 *= __fdividef(1.0f, (r3a.x+r3a.y+r3a.z+r3a.w) + (r3b.x+r3b.y+r3b.z+r3b.w));
    }

    attn_out[mrow]         = p0;
    attn_out[mrow + SEQ]   = p1;
    attn_out[mrow + 2*SEQ] = p2;
    attn_out[mrow + 3*SEQ] = p3;
    s_p[0][tid] = p0; s_p[1][tid] = p1; s_p[2][tid] = p2; s_p[3][tid] = p3;
    __syncthreads();

    // ---- av: out[i_r, d] = sum_j p_r[j] * h[b,j,d], 4 rows share h loads ----
    const int dq = tid & 63;                                    // 4-d quad
    const int js = __builtin_amdgcn_readfirstlane(tid >> 6);    // 0..7 -> 64-j slice
    const float* __restrict__ hp = h + (size_t)(b * SEQ + js * 64) * DM + 4 * dq;
    const float* __restrict__ q0p = &s_p[0][js * 64];
    const float* __restrict__ q1p = &s_p[1][js * 64];
    const float* __restrict__ q2p = &s_p[2][js * 64];
    const float* __restrict__ q3p = &s_p[3][js * 64];

    float4 a0v = make_float4(0,0,0,0), a1v = a0v, a2v = a0v, a3v = a0v;
    #pragma unroll 4
    for (int jj = 0; jj < 16; jj++) {
        const float4 P0 = *(const float4*)(q0p + 4 * jj);   // b128 broadcast
        const float4 P1 = *(const float4*)(q1p + 4 * jj);
        const float4 P2 = *(const float4*)(q2p + 4 * jj);
        const float4 P3 = *(const float4*)(q3p + 4 * jj);
        const float4 h0 = *(const float4*)(hp + (size_t)(4*jj + 0) * DM);
        const float4 h1 = *(const float4*)(hp + (size_t)(4*jj + 1) * DM);
        const float4 h2 = *(const float4*)(hp + (size_t)(4*jj + 2) * DM);
        const float4 h3 = *(const float4*)(hp + (size_t)(4*jj + 3) * DM);

        a0v.x = fmaf(P0.x,h0.x,fmaf(P0.y,h1.x,fmaf(P0.z,h2.x,fmaf(P0.w,h3.x,a0v.x))));
        a0v.y = fmaf(P0.x,h0.y,fmaf(P0.y,h1.y,fmaf(P0.z,h2.y,fmaf(P0.w,h3.y,a0v.y))));
        a0v.z = fmaf(P0.x,h0.z,fmaf(P0.y,h1.z,fmaf(P0.z,h2.z,fmaf(P0.w,h3.z,a0v.z))));
        a0v.w = fmaf(P0.x,h0.w,fmaf(P0.y,h1.w,fmaf(P0.z,h2.w,fmaf(P0.w,h3.w,a0v.w))));
        a1v.x = fmaf(P1.x,h0.x,fmaf(P1.y,h1.x,fmaf(P1.z,h2.x,fmaf(P1.w,h3.x,a1v.x))));
        a1v.y = fmaf(P1.x,h0.y,fmaf(P1.y,h1.y,fmaf(P1.z,h2.y,fmaf(P1.w,h3.y,a1v.y))));
        a1v.z = fmaf(P1.x,h0.z,fmaf(P1.y,h1.z,fmaf(P1.z,h2.z,fmaf(P1.w,h3.z,a1v.z))));
        a1v.w = fmaf(P1.x,h0.w,fmaf(P1.y,h1.w,fmaf(P1.z,h2.w,fmaf(P1.w,h3.w,a1v.w))));
        a2v.x = fmaf(P2.x,h0.x,fmaf(P2.y,h1.x,fmaf(P2.z,h2.x,fmaf(P2.w,h3.x,a2v.x))));
        a2v.y = fmaf(P2.x,h0.y,fmaf(P2.y,h1.y,fmaf(P2.z,h2.y,fmaf(P2.w,h3.y,a2v.y))));
        a2v.z = fmaf(P2.x,h0.z,fmaf(P2.y,h1.z,fmaf(P2.z,h2.z,fmaf(P2.w,h3.z,a2v.z))));
        a2v.w = fmaf(P2.x,h0.w,fmaf(P2.y,h1.w,fmaf(P2.z,h2.w,fmaf(P2.w,h3.w,a2v.w))));
        a3v.x = fmaf(P3.x,h0.x,fmaf(P3.y,h1.x,fmaf(P3.z,h2.x,fmaf(P3.w,h3.x,a3v.x))));
        a3v.y = fmaf(P3.x,h0.y,fmaf(P3.y,h1.y,fmaf(P3.z,h2.y,fmaf(P3.w,h3.y,a3v.y))));
        a3v.z = fmaf(P3.x,h0.z,fmaf(P3.y,h1.z,fmaf(P3.z,h2.z,fmaf(P3.w,h3.z,a3v.z))));
        a3v.w = fmaf(P3.x,h0.w,fmaf(P3.y,h1.w,fmaf(P3.z,h2.w,fmaf(P3.w,h3.w,a3v.w))));
    }

    if (js > 0) {
        *(float4*)&s_o[js - 1][0][4 * dq] = a0v;
        *(float4*)&s_o[js - 1][1][4 * dq] = a1v;
        *(float4*)&s_o[js - 1][2][4 * dq] = a2v;
        *(float4*)&s_o[js - 1][3][4 * dq] = a3v;
    }
    __syncthreads();
    if (js == 0) {
        #pragma unroll
        for (int s = 0; s < 7; s++) {
            const float4 q0 = *(const float4*)&s_o[s][0][4 * dq];
            const float4 q1 = *(const float4*)&s_o[s][1][4 * dq];
            const float4 q2 = *(const float4*)&s_o[s][2][4 * dq];
            const float4 q3 = *(const float4*)&s_o[s][3][4 * dq];
            a0v.x += q0.x; a0v.y += q0.y; a0v.z += q0.z; a0v.w += q0.w;
            a1v.x += q1.x; a1v.y += q1.y; a1v.z += q1.z; a1v.w += q1.w;
            a2v.x += q2.x; a2v.y += q2.y; a2v.z += q2.z; a2v.w += q2.w;
            a3v.x += q3.x; a3v.y += q3.y; a3v.z += q3.z; a3v.w += q3.w;
        }
        float* __restrict__ op = out + (size_t)(b * SEQ + i0) * DM + 4 * dq;
        *(float4*)(op)        = a0v;
        *(float4*)(op + DM)   = a1v;
        *(float4*)(op + 2*DM) = a2v;
        *(float4*)(op + 3*DM) = a3v;
    }
}

extern "C" void kernel_launch(void* const* d_in, const int* in_sizes, int n_in,
                              void* d_out, int out_size, void* d_ws, size_t ws_size,
                              hipStream_t stream) {
    const float* x    = (const float*)d_in[0];
    const float* pos  = (const float*)d_in[1];
    const int*   mask = (const int*)  d_in[2];
    const float* Wx   = (const float*)d_in[3];
    const float* bx   = (const float*)d_in[4];
    const float* Wp   = (const float*)d_in[5];
    const float* bp   = (const float*)d_in[6];
    const float* wv   = (const float*)d_in[7];

    float* out      = (float*)d_out;                          // [B,N,DM]
    float* attn_out = (float*)d_out + (size_t)BATCH*SEQ*DM;   // [B,N,N]

    char*  ws  = (char*)d_ws;
    float* h   = (float*)(ws);                                // 1 MB
    float* EBf = (float*)(ws + (size_t)BATCH*SEQ*DM*4);       // 1 MB ([B][DM4][SEQ] float4)

    produce_k<<<256, 512, 0, stream>>>(pos, Wp, x, Wx, bx, (float4*)EBf, h);
    attend_k <<<(BATCH*SEQ)/4, 512, 0, stream>>>(pos, Wp, bp, mask, wv,
                                                 (const float4*)EBf, h, out, attn_out);
}